// Round 11
// baseline (545.107 us; speedup 1.0000x reference)
//
#include <hip/hip_runtime.h>
#include <hip/hip_fp16.h>

#define D 64

// ---------------------------------------------------------------------------
// Kernel 1 (fused): blocks [0, nGemmBlocks) compute support = x @ W (fp16 out);
// blocks [nGemmBlocks, ...) build CSR row_ptr from sorted edge_row.
// (byte-identical to rounds 3-5 — clean A/B on the spmm rewrite)
// ---------------------------------------------------------------------------
__global__ __launch_bounds__(256, 3) void gemm_and_rowptr(
    const float* __restrict__ x, const float* __restrict__ w,
    __half* __restrict__ sup, int N,
    const int* __restrict__ erow, int* __restrict__ rptr, int E,
    int nGemmBlocks) {
  if ((int)blockIdx.x >= nGemmBlocks) {
    const int e = (blockIdx.x - nGemmBlocks) * 256 + threadIdx.x;
    if (e < E) {
      const int r = erow[e];
      const int rprev = (e == 0) ? -1 : erow[e - 1];
      for (int q = rprev + 1; q <= r; ++q) rptr[q] = e;
      if (e == E - 1)
        for (int q = r + 1; q <= N; ++q) rptr[q] = E;
    }
    return;
  }

  __shared__ alignas(16) float ws[D * D];    // 16 KB
  __shared__ alignas(16) float xs[128 * D];  // 32 KB (swizzled)
  const int tid = threadIdx.x;
  const int rowBase = blockIdx.x * 128;

#pragma unroll
  for (int i = 0; i < 4; ++i) {
    const int idx = i * 1024 + tid * 4;
    *(float4*)&ws[idx] = *(const float4*)&w[idx];
  }
#pragma unroll
  for (int i = 0; i < 8; ++i) {
    const int idx = i * 1024 + tid * 4;
    const int rl = idx >> 6;
    const int c = idx & 63;
    const int r = rowBase + rl;
    float4 v = make_float4(0.f, 0.f, 0.f, 0.f);
    if (r < N) v = *(const float4*)&x[(size_t)r * D + c];
    const int M = ((rl >> 2) & 15) << 2;
    *(float4*)&xs[rl * D + (c ^ M)] = v;
  }
  __syncthreads();

  const int cg = tid & 7;
  const int rg = tid >> 3;
  const int M = (rg & 15) << 2;
  const int cb = cg << 3;

  float4 A00 = make_float4(0.f, 0.f, 0.f, 0.f), A01 = A00;
  float4 A10 = A00, A11 = A00, A20 = A00, A21 = A00, A30 = A00, A31 = A00;

#pragma unroll 4
  for (int k = 0; k < D; ++k) {
    const float4 w0 = *(const float4*)&ws[k * D + cb];
    const float4 w1 = *(const float4*)&ws[k * D + cb + 4];
    const int kk = k ^ M;
    const float x0 = xs[(rg * 4 + 0) * D + kk];
    const float x1 = xs[(rg * 4 + 1) * D + kk];
    const float x2 = xs[(rg * 4 + 2) * D + kk];
    const float x3 = xs[(rg * 4 + 3) * D + kk];
    A00.x = fmaf(w0.x, x0, A00.x); A00.y = fmaf(w0.y, x0, A00.y);
    A00.z = fmaf(w0.z, x0, A00.z); A00.w = fmaf(w0.w, x0, A00.w);
    A01.x = fmaf(w1.x, x0, A01.x); A01.y = fmaf(w1.y, x0, A01.y);
    A01.z = fmaf(w1.z, x0, A01.z); A01.w = fmaf(w1.w, x0, A01.w);
    A10.x = fmaf(w0.x, x1, A10.x); A10.y = fmaf(w0.y, x1, A10.y);
    A10.z = fmaf(w0.z, x1, A10.z); A10.w = fmaf(w0.w, x1, A10.w);
    A11.x = fmaf(w1.x, x1, A11.x); A11.y = fmaf(w1.y, x1, A11.y);
    A11.z = fmaf(w1.z, x1, A11.z); A11.w = fmaf(w1.w, x1, A11.w);
    A20.x = fmaf(w0.x, x2, A20.x); A20.y = fmaf(w0.y, x2, A20.y);
    A20.z = fmaf(w0.z, x2, A20.z); A20.w = fmaf(w0.w, x2, A20.w);
    A21.x = fmaf(w1.x, x2, A21.x); A21.y = fmaf(w1.y, x2, A21.y);
    A21.z = fmaf(w1.z, x2, A21.z); A21.w = fmaf(w1.w, x2, A21.w);
    A30.x = fmaf(w0.x, x3, A30.x); A30.y = fmaf(w0.y, x3, A30.y);
    A30.z = fmaf(w0.z, x3, A30.z); A30.w = fmaf(w0.w, x3, A30.w);
    A31.x = fmaf(w1.x, x3, A31.x); A31.y = fmaf(w1.y, x3, A31.y);
    A31.z = fmaf(w1.z, x3, A31.z); A31.w = fmaf(w1.w, x3, A31.w);
  }

#define STORE_ROW(i, L, R)                                          \
  {                                                                 \
    const int r = rowBase + rg * 4 + (i);                           \
    if (r < N) {                                                    \
      __half2 h[4];                                                 \
      h[0] = __floats2half2_rn((L).x, (L).y);                       \
      h[1] = __floats2half2_rn((L).z, (L).w);                       \
      h[2] = __floats2half2_rn((R).x, (R).y);                       \
      h[3] = __floats2half2_rn((R).z, (R).w);                       \
      *(float4*)&sup[(size_t)r * D + cb] = *(float4*)h;             \
    }                                                               \
  }
  STORE_ROW(0, A00, A01)
  STORE_ROW(1, A10, A11)
  STORE_ROW(2, A20, A21)
  STORE_ROW(3, A30, A31)
#undef STORE_ROW
}

// ---------------------------------------------------------------------------
// Kernel 2 (v3): edge-parallel SpMM with LDS fp32 accumulation.
// Block owns 64 output rows (edges contiguous, via rp). Each 8-lane group
// processes one edge per iteration: group-broadcast metadata, one coalesced
// float4 (16B = 8 fp16 cols) gather per lane (8 edges per wave instruction),
// scale by val, ds_add_f32 into a [64][65] fp32 LDS tile (+1 pad => ~2-way
// banks, free). Iterations independent => gathers stream with no per-row
// drain. Epilogue: coalesced float4 stores with fused ReLU.
// ---------------------------------------------------------------------------
__global__ __launch_bounds__(256) void spmm_relu_v3(
    const float4* __restrict__ sup4,  // fp16 rows: 8 float4 per row
    const int* __restrict__ rp, const int* __restrict__ erow,
    const int* __restrict__ ecol, const float* __restrict__ eval,
    float* __restrict__ out, int N) {
  __shared__ float acc[64 * 65];
  const int tid = threadIdx.x;

#pragma unroll
  for (int i = 0; i < 17; ++i) {  // 64*65 = 4160 = 16.25 * 256
    const int idx = i * 256 + tid;
    if (idx < 64 * 65) acc[idx] = 0.f;
  }
  __syncthreads();

  const int rowBase = blockIdx.x * 64;
  const int rowEnd = (rowBase + 64 < N) ? rowBase + 64 : N;
  const int s = __builtin_amdgcn_readfirstlane(rp[rowBase]);
  const int e = __builtin_amdgcn_readfirstlane(rp[rowEnd]);

  const int gid = tid >> 3;  // edge group 0..31
  const int lg = tid & 7;    // column slice: cols 8*lg .. 8*lg+7

#pragma unroll 2
  for (int i = s + gid; i < e; i += 32) {
    const int r = erow[i] - rowBase;  // 0..63 (broadcast within group)
    const int c = ecol[i];
    const float v = eval[i];
    const float4 q = sup4[(size_t)c * 8 + lg];
    const __half2* h = (const __half2*)&q;
    const float2 f0 = __half22float2(h[0]);
    const float2 f1 = __half22float2(h[1]);
    const float2 f2 = __half22float2(h[2]);
    const float2 f3 = __half22float2(h[3]);
    float* a = &acc[r * 65 + lg * 8];
    atomicAdd(&a[0], f0.x * v);
    atomicAdd(&a[1], f0.y * v);
    atomicAdd(&a[2], f1.x * v);
    atomicAdd(&a[3], f1.y * v);
    atomicAdd(&a[4], f2.x * v);
    atomicAdd(&a[5], f2.y * v);
    atomicAdd(&a[6], f3.x * v);
    atomicAdd(&a[7], f3.y * v);
  }
  __syncthreads();

  // Epilogue: 4 passes of 256 float4 (16 rows x 16 float4-per-row each pass).
  // Lane addresses consecutive 16B => perfectly coalesced 1KB/wave-instr.
#pragma unroll
  for (int u = 0; u < 4; ++u) {
    const int rl = u * 16 + (tid >> 4);  // local row
    const int c4 = (tid & 15) * 4;       // col (multiple of 4)
    const int r = rowBase + rl;
    if (r < N) {
      const float* a = &acc[rl * 65 + c4];
      float4 o;
      o.x = fmaxf(a[0], 0.f);
      o.y = fmaxf(a[1], 0.f);
      o.z = fmaxf(a[2], 0.f);
      o.w = fmaxf(a[3], 0.f);
      *(float4*)&out[(size_t)r * D + c4] = o;
    }
  }
}

// ---------------------------------------------------------------------------
extern "C" void kernel_launch(void* const* d_in, const int* in_sizes, int n_in,
                              void* d_out, int out_size, void* d_ws, size_t ws_size,
                              hipStream_t stream) {
  const float* x = (const float*)d_in[0];
  const float* w = (const float*)d_in[1];
  const int* erow = (const int*)d_in[2];
  const int* ecol = (const int*)d_in[3];
  const float* eval = (const float*)d_in[4];
  float* out = (float*)d_out;

  const int N = in_sizes[0] / D;  // 100000
  const int E = in_sizes[2];      // 1200000

  __half* sup = (__half*)d_ws;  // N*64 fp16 = 12.8 MB
  int* rp = (int*)((char*)d_ws + (((size_t)N * D * sizeof(__half) + 255) & ~(size_t)255));

  const int nGemmBlocks = (N + 127) / 128;
  const int nRpBlocks = (E + 255) / 256;

  gemm_and_rowptr<<<nGemmBlocks + nRpBlocks, 256, 0, stream>>>(
      x, w, sup, N, erow, rp, E, nGemmBlocks);
  spmm_relu_v3<<<(N + 63) / 64, 256, 0, stream>>>(
      (const float4*)sup, rp, erow, ecol, eval, out, N);
}

// Round 12
// 131.024 us; speedup vs baseline: 4.1604x; 4.1604x over previous
//
#include <hip/hip_runtime.h>
#include <hip/hip_fp16.h>

#define D 64

// ---------------------------------------------------------------------------
// Kernel 1 (fused): blocks [0, nGemmBlocks) compute support = x @ W (fp16 out);
// blocks [nGemmBlocks, ...) build CSR row_ptr from sorted edge_row.
// Only change vs rounds 3-5: __launch_bounds__(256,4) caps VGPR at 128
// (round-2 variant was VGPR=240 @ 9.4% occupancy; ~70 live regs suffice).
// ---------------------------------------------------------------------------
__global__ __launch_bounds__(256, 4) void gemm_and_rowptr(
    const float* __restrict__ x, const float* __restrict__ w,
    __half* __restrict__ sup, int N,
    const int* __restrict__ erow, int* __restrict__ rptr, int E,
    int nGemmBlocks) {
  if ((int)blockIdx.x >= nGemmBlocks) {
    const int e = (blockIdx.x - nGemmBlocks) * 256 + threadIdx.x;
    if (e < E) {
      const int r = erow[e];
      const int rprev = (e == 0) ? -1 : erow[e - 1];
      for (int q = rprev + 1; q <= r; ++q) rptr[q] = e;
      if (e == E - 1)
        for (int q = r + 1; q <= N; ++q) rptr[q] = E;
    }
    return;
  }

  __shared__ alignas(16) float ws[D * D];    // 16 KB
  __shared__ alignas(16) float xs[128 * D];  // 32 KB (swizzled)
  const int tid = threadIdx.x;
  const int rowBase = blockIdx.x * 128;

#pragma unroll
  for (int i = 0; i < 4; ++i) {
    const int idx = i * 1024 + tid * 4;
    *(float4*)&ws[idx] = *(const float4*)&w[idx];
  }
#pragma unroll
  for (int i = 0; i < 8; ++i) {
    const int idx = i * 1024 + tid * 4;
    const int rl = idx >> 6;
    const int c = idx & 63;
    const int r = rowBase + rl;
    float4 v = make_float4(0.f, 0.f, 0.f, 0.f);
    if (r < N) v = *(const float4*)&x[(size_t)r * D + c];
    const int M = ((rl >> 2) & 15) << 2;
    *(float4*)&xs[rl * D + (c ^ M)] = v;
  }
  __syncthreads();

  const int cg = tid & 7;
  const int rg = tid >> 3;
  const int M = (rg & 15) << 2;
  const int cb = cg << 3;

  float4 A00 = make_float4(0.f, 0.f, 0.f, 0.f), A01 = A00;
  float4 A10 = A00, A11 = A00, A20 = A00, A21 = A00, A30 = A00, A31 = A00;

#pragma unroll 4
  for (int k = 0; k < D; ++k) {
    const float4 w0 = *(const float4*)&ws[k * D + cb];
    const float4 w1 = *(const float4*)&ws[k * D + cb + 4];
    const int kk = k ^ M;
    const float x0 = xs[(rg * 4 + 0) * D + kk];
    const float x1 = xs[(rg * 4 + 1) * D + kk];
    const float x2 = xs[(rg * 4 + 2) * D + kk];
    const float x3 = xs[(rg * 4 + 3) * D + kk];
    A00.x = fmaf(w0.x, x0, A00.x); A00.y = fmaf(w0.y, x0, A00.y);
    A00.z = fmaf(w0.z, x0, A00.z); A00.w = fmaf(w0.w, x0, A00.w);
    A01.x = fmaf(w1.x, x0, A01.x); A01.y = fmaf(w1.y, x0, A01.y);
    A01.z = fmaf(w1.z, x0, A01.z); A01.w = fmaf(w1.w, x0, A01.w);
    A10.x = fmaf(w0.x, x1, A10.x); A10.y = fmaf(w0.y, x1, A10.y);
    A10.z = fmaf(w0.z, x1, A10.z); A10.w = fmaf(w0.w, x1, A10.w);
    A11.x = fmaf(w1.x, x1, A11.x); A11.y = fmaf(w1.y, x1, A11.y);
    A11.z = fmaf(w1.z, x1, A11.z); A11.w = fmaf(w1.w, x1, A11.w);
    A20.x = fmaf(w0.x, x2, A20.x); A20.y = fmaf(w0.y, x2, A20.y);
    A20.z = fmaf(w0.z, x2, A20.z); A20.w = fmaf(w0.w, x2, A20.w);
    A21.x = fmaf(w1.x, x2, A21.x); A21.y = fmaf(w1.y, x2, A21.y);
    A21.z = fmaf(w1.z, x2, A21.z); A21.w = fmaf(w1.w, x2, A21.w);
    A30.x = fmaf(w0.x, x3, A30.x); A30.y = fmaf(w0.y, x3, A30.y);
    A30.z = fmaf(w0.z, x3, A30.z); A30.w = fmaf(w0.w, x3, A30.w);
    A31.x = fmaf(w1.x, x3, A31.x); A31.y = fmaf(w1.y, x3, A31.y);
    A31.z = fmaf(w1.z, x3, A31.z); A31.w = fmaf(w1.w, x3, A31.w);
  }

#define STORE_ROW(i, L, R)                                          \
  {                                                                 \
    const int r = rowBase + rg * 4 + (i);                           \
    if (r < N) {                                                    \
      __half2 h[4];                                                 \
      h[0] = __floats2half2_rn((L).x, (L).y);                       \
      h[1] = __floats2half2_rn((L).z, (L).w);                       \
      h[2] = __floats2half2_rn((R).x, (R).y);                       \
      h[3] = __floats2half2_rn((R).z, (R).w);                       \
      *(float4*)&sup[(size_t)r * D + cb] = *(float4*)h;             \
    }                                                               \
  }
  STORE_ROW(0, A00, A01)
  STORE_ROW(1, A10, A11)
  STORE_ROW(2, A20, A21)
  STORE_ROW(3, A30, A31)
#undef STORE_ROW
}

// ---------------------------------------------------------------------------
// Kernel 2: out[r,:] = relu( sum_{e in row r} val[e] * sup[col[e],:] )
// Round-5 version (best measured). One wave per TWO consecutive rows,
// software-pipelined metadata + gathers; 8 lanes per edge, float4 gathers;
// 3-level shfl_xor reduce; lanes 0-7 store with fused ReLU.
// ---------------------------------------------------------------------------

#define DECL_ACC(p)                                                   \
  float p##_0 = 0.f, p##_1 = 0.f, p##_2 = 0.f, p##_3 = 0.f,           \
        p##_4 = 0.f, p##_5 = 0.f, p##_6 = 0.f, p##_7 = 0.f;

#define ACCUM(p, Q, V)                                                \
  {                                                                   \
    const __half2* h_ = (const __half2*)&(Q);                         \
    const float2 f0_ = __half22float2(h_[0]);                         \
    const float2 f1_ = __half22float2(h_[1]);                         \
    const float2 f2_ = __half22float2(h_[2]);                         \
    const float2 f3_ = __half22float2(h_[3]);                         \
    p##_0 = fmaf(f0_.x, (V), p##_0); p##_1 = fmaf(f0_.y, (V), p##_1); \
    p##_2 = fmaf(f1_.x, (V), p##_2); p##_3 = fmaf(f1_.y, (V), p##_3); \
    p##_4 = fmaf(f2_.x, (V), p##_4); p##_5 = fmaf(f2_.y, (V), p##_5); \
    p##_6 = fmaf(f3_.x, (V), p##_6); p##_7 = fmaf(f3_.y, (V), p##_7); \
  }

#define REDUCE_STORE(p, r)                                            \
  {                                                                   \
    p##_0 += __shfl_xor(p##_0, 8);  p##_0 += __shfl_xor(p##_0, 16);   \
    p##_0 += __shfl_xor(p##_0, 32);                                   \
    p##_1 += __shfl_xor(p##_1, 8);  p##_1 += __shfl_xor(p##_1, 16);   \
    p##_1 += __shfl_xor(p##_1, 32);                                   \
    p##_2 += __shfl_xor(p##_2, 8);  p##_2 += __shfl_xor(p##_2, 16);   \
    p##_2 += __shfl_xor(p##_2, 32);                                   \
    p##_3 += __shfl_xor(p##_3, 8);  p##_3 += __shfl_xor(p##_3, 16);   \
    p##_3 += __shfl_xor(p##_3, 32);                                   \
    p##_4 += __shfl_xor(p##_4, 8);  p##_4 += __shfl_xor(p##_4, 16);   \
    p##_4 += __shfl_xor(p##_4, 32);                                   \
    p##_5 += __shfl_xor(p##_5, 8);  p##_5 += __shfl_xor(p##_5, 16);   \
    p##_5 += __shfl_xor(p##_5, 32);                                   \
    p##_6 += __shfl_xor(p##_6, 8);  p##_6 += __shfl_xor(p##_6, 16);   \
    p##_6 += __shfl_xor(p##_6, 32);                                   \
    p##_7 += __shfl_xor(p##_7, 8);  p##_7 += __shfl_xor(p##_7, 16);   \
    p##_7 += __shfl_xor(p##_7, 32);                                   \
    if (g == 0) {                                                     \
      float4 o0, o1;                                                  \
      o0.x = fmaxf(p##_0, 0.f); o0.y = fmaxf(p##_1, 0.f);             \
      o0.z = fmaxf(p##_2, 0.f); o0.w = fmaxf(p##_3, 0.f);             \
      o1.x = fmaxf(p##_4, 0.f); o1.y = fmaxf(p##_5, 0.f);             \
      o1.z = fmaxf(p##_6, 0.f); o1.w = fmaxf(p##_7, 0.f);             \
      float* po = &out[(size_t)(r)*D + lg * 8];                       \
      *(float4*)po = o0;                                              \
      *(float4*)(po + 4) = o1;                                        \
    }                                                                 \
  }

#define ROW_GENERAL(r, s, deg, myc, myv)                              \
  {                                                                   \
    DECL_ACC(t)                                                       \
    const int K = (deg) < 64 ? (deg) : 64;                            \
    for (int jb = 0; jb < K; jb += 16) {                              \
      const int j0 = jb + g, j1 = jb + 8 + g;                         \
      int c0 = __shfl((myc), j0); float v0 = __shfl((myv), j0);       \
      int c1 = __shfl((myc), j1); float v1 = __shfl((myv), j1);       \
      if (j0 >= K) { c0 = 0; v0 = 0.f; }                              \
      if (j1 >= K) { c1 = 0; v1 = 0.f; }                              \
      const float4 q0 = sup4[(size_t)c0 * 8 + lg];                    \
      const float4 q1 = sup4[(size_t)c1 * 8 + lg];                    \
      ACCUM(t, q0, v0)                                                \
      ACCUM(t, q1, v1)                                                \
    }                                                                 \
    for (int j = 64; j < (deg); j += 8) {                             \
      int c = 0; float v = 0.f;                                       \
      if (j + g < (deg)) { c = col[(s) + j + g]; v = val[(s) + j + g]; } \
      const float4 q = sup4[(size_t)c * 8 + lg];                      \
      ACCUM(t, q, v)                                                  \
    }                                                                 \
    REDUCE_STORE(t, r)                                                \
  }

__global__ __launch_bounds__(256) void spmm_relu(
    const float4* __restrict__ sup4,  // fp16 rows: 8 float4 per row
    const int* __restrict__ rp, const int* __restrict__ col,
    const float* __restrict__ val, float* __restrict__ out, int N) {
  const int lane = threadIdx.x & 63;
  const int g = lane >> 3;  // edge slot (0..7)
  const int lg = lane & 7;  // column slice: cols 8*lg .. 8*lg+7
  const int r0 = (blockIdx.x * 4 + (threadIdx.x >> 6)) * 2;
  if (r0 >= N) return;
  const int r1 = r0 + 1;
  const bool has1 = r1 < N;

  const int s0 = __builtin_amdgcn_readfirstlane(rp[r0]);
  const int e0 = __builtin_amdgcn_readfirstlane(rp[r0 + 1]);
  int e1 = e0;
  if (has1) e1 = __builtin_amdgcn_readfirstlane(rp[r0 + 2]);
  const int s1 = e0;
  const int deg0 = e0 - s0;
  const int deg1 = e1 - s1;

  // Metadata prefetch for BOTH rows — 4 independent coalesced loads in flight.
  int myc0 = 0, myc1 = 0;
  float myv0 = 0.f, myv1 = 0.f;
  if (lane < deg0) { myc0 = col[s0 + lane]; myv0 = val[s0 + lane]; }
  if (lane < deg1) { myc1 = col[s1 + lane]; myv1 = val[s1 + lane]; }

  if (deg0 <= 16 && deg1 <= 16 && has1) {
    // Fast path (~80% of row pairs): all 4 gather instructions issue
    // back-to-back before any consumption — both rows' misses overlap.
    const int j0 = g, j1 = 8 + g;
    int c00 = __shfl(myc0, j0); float v00 = __shfl(myv0, j0);
    int c01 = __shfl(myc0, j1); float v01 = __shfl(myv0, j1);
    int c10 = __shfl(myc1, j0); float v10 = __shfl(myv1, j0);
    int c11 = __shfl(myc1, j1); float v11 = __shfl(myv1, j1);
    if (j0 >= deg0) { c00 = 0; v00 = 0.f; }
    if (j1 >= deg0) { c01 = 0; v01 = 0.f; }
    if (j0 >= deg1) { c10 = 0; v10 = 0.f; }
    if (j1 >= deg1) { c11 = 0; v11 = 0.f; }
    const float4 q00 = sup4[(size_t)c00 * 8 + lg];
    const float4 q01 = sup4[(size_t)c01 * 8 + lg];
    const float4 q10 = sup4[(size_t)c10 * 8 + lg];
    const float4 q11 = sup4[(size_t)c11 * 8 + lg];
    {
      DECL_ACC(a)
      ACCUM(a, q00, v00)
      ACCUM(a, q01, v01)
      REDUCE_STORE(a, r0)
    }
    {
      DECL_ACC(b)
      ACCUM(b, q10, v10)
      ACCUM(b, q11, v11)
      REDUCE_STORE(b, r1)
    }
    return;
  }

  // General path: rows processed sequentially (round-4 structure).
  ROW_GENERAL(r0, s0, deg0, myc0, myv0)
  if (has1) ROW_GENERAL(r1, s1, deg1, myc1, myv1)
}

#undef ROW_GENERAL
#undef REDUCE_STORE
#undef ACCUM
#undef DECL_ACC

// ---------------------------------------------------------------------------
extern "C" void kernel_launch(void* const* d_in, const int* in_sizes, int n_in,
                              void* d_out, int out_size, void* d_ws, size_t ws_size,
                              hipStream_t stream) {
  const float* x = (const float*)d_in[0];
  const float* w = (const float*)d_in[1];
  const int* erow = (const int*)d_in[2];
  const int* ecol = (const int*)d_in[3];
  const float* eval = (const float*)d_in[4];
  float* out = (float*)d_out;

  const int N = in_sizes[0] / D;  // 100000
  const int E = in_sizes[2];      // 1200000

  __half* sup = (__half*)d_ws;  // N*64 fp16 = 12.8 MB
  int* rp = (int*)((char*)d_ws + (((size_t)N * D * sizeof(__half) + 255) & ~(size_t)255));

  const int nGemmBlocks = (N + 127) / 128;
  const int nRpBlocks = (E + 255) / 256;

  gemm_and_rowptr<<<nGemmBlocks + nRpBlocks, 256, 0, stream>>>(
      x, w, sup, N, erow, rp, E, nGemmBlocks);
  spmm_relu<<<(N + 7) / 8, 256, 0, stream>>>((const float4*)sup, rp, ecol, eval,
                                             out, N);
}